// Round 6
// baseline (252.085 us; speedup 1.0000x reference)
//
#include <hip/hip_runtime.h>
#include <hip/hip_bf16.h>

typedef unsigned short u16;
typedef __attribute__((ext_vector_type(8))) short short8;
typedef __attribute__((ext_vector_type(4))) float f32x4;

#define B_SZ 16
#define S_SZ 512
#define D_SZ 1024
#define H_SZ 16
#define DH_SZ 64
#define M_SZ (B_SZ * S_SZ)      // 8192
#define EXPSCALE 0.18033688f    // 0.125 * log2(e)

// direct global->LDS DMA, 16B per lane; LDS dest = wave-uniform base + lane*16
__device__ __forceinline__ void gload_lds16(const void* g, void* l) {
  __builtin_amdgcn_global_load_lds(
      (const __attribute__((address_space(1))) unsigned int*)g,
      (__attribute__((address_space(3))) unsigned int*)l,
      16, 0, 0);
}

// ---------------------------------------------------------------------------
// prep: fused f32->bf16 cast of v (blocks 0..8191) + weight transpose+downcast
// ---------------------------------------------------------------------------
__global__ __launch_bounds__(256) void prep(
    const float* __restrict__ v, u16* __restrict__ vB,
    const float* __restrict__ W0, const float* __restrict__ W1,
    const float* __restrict__ W2, const float* __restrict__ W3,
    u16* __restrict__ T0, u16* __restrict__ T1,
    u16* __restrict__ T2, u16* __restrict__ T3) {
  __shared__ float tile[32][33];
  const int bid = blockIdx.x;
  if (bid < 8192) {
    int i = bid * 256 + threadIdx.x;
    const float4 f = *(const float4*)&v[(size_t)i * 4];
    ushort4 o; __hip_bfloat16 h;
    h = __float2bfloat16(f.x); o.x = *(u16*)&h;
    h = __float2bfloat16(f.y); o.y = *(u16*)&h;
    h = __float2bfloat16(f.z); o.z = *(u16*)&h;
    h = __float2bfloat16(f.w); o.w = *(u16*)&h;
    *(ushort4*)&vB[(size_t)i * 4] = o;
    return;
  }
  const int tb = bid - 8192;
  const int z = tb >> 10, rem = tb & 1023;
  const int by = rem >> 5, bx = rem & 31;
  const float* W; u16* T;
  switch (z) {
    case 0: W = W0; T = T0; break;
    case 1: W = W1; T = T1; break;
    case 2: W = W2; T = T2; break;
    default: W = W3; T = T3; break;
  }
  int tx = threadIdx.x & 31, ty = threadIdx.x >> 5;  // 32 x 8
  int x = bx * 32 + tx;
#pragma unroll
  for (int i = 0; i < 32; i += 8)
    tile[ty + i][tx] = W[(size_t)(by * 32 + ty + i) * 1024 + x];
  __syncthreads();
  int x2 = by * 32 + tx;
#pragma unroll
  for (int i = 0; i < 32; i += 8) {
    __hip_bfloat16 h = __float2bfloat16(tile[tx][ty + i]);
    T[(size_t)(bx * 32 + ty + i) * 1024 + x2] = *(u16*)&h;
  }
}

// ---------------------------------------------------------------------------
// GEMM core: BK=32, corrected XOR chunk swizzle. LDS tile 128 x 32 (64B row,
// 4 chunks); physical chunk p of row r holds logical chunk p ^ ((r>>1)&3).
// Fragment reads then hit each 4-bank group exactly 2-way (free, m136).
// ---------------------------------------------------------------------------
__device__ __forceinline__ void gemm_core32(
    const u16* __restrict__ A, const u16* __restrict__ Bt,
    u16* As, u16* Bs, int m0, int n0, f32x4 acc[4][4]) {
  const int t = threadIdx.x;
  const int lane = t & 63, wave = t >> 6;
  const int r4 = lane >> 2;                          // row within 16-row segment
  const int gcol = ((lane & 3) ^ ((r4 >> 1) & 3)) * 8;  // swizzled source chunk
  const int wm = (wave >> 1) * 64, wn = (wave & 1) * 64;
  const int c = lane & 15, quad = lane >> 4;
  const int pc = (quad ^ ((c >> 1) & 3)) * 8;        // physical chunk for frag read

  for (int k0 = 0; k0 < 1024; k0 += 32) {
    __syncthreads();
#pragma unroll
    for (int i = 0; i < 2; ++i) {
      int seg = wave * 2 + i;                        // 8 segs x 16 rows = 128 rows
      int row = seg * 16 + r4;
      gload_lds16(&A[(size_t)(m0 + row) * 1024 + k0 + gcol], &As[seg * 512]);
      gload_lds16(&Bt[(size_t)(n0 + row) * 1024 + k0 + gcol], &Bs[seg * 512]);
    }
    __syncthreads();

    short8 af[4], bf[4];
#pragma unroll
    for (int i = 0; i < 4; ++i) {
      af[i] = *(const short8*)&As[(wm + i * 16 + c) * 32 + pc];
      bf[i] = *(const short8*)&Bs[(wn + i * 16 + c) * 32 + pc];
    }
#pragma unroll
    for (int mi = 0; mi < 4; ++mi)
#pragma unroll
      for (int ni = 0; ni < 4; ++ni)
        acc[mi][ni] = __builtin_amdgcn_mfma_f32_16x16x32_bf16(
            af[mi], bf[ni], acc[mi][ni], 0, 0, 0);
  }
}

// ---------------------------------------------------------------------------
// Fused QKV GEMM. Grid (64 m, 8 n, 3 z) -> XCD = blockid%8 pins A-stripes.
// z=0 -> Q row-major; z=1 -> Kt[b][h][s][d]; z=2 -> Vt[b][h][d][s]
// ---------------------------------------------------------------------------
__global__ __launch_bounds__(256) void gemm_qkv(
    const u16* __restrict__ A,
    const u16* __restrict__ BtQ, const u16* __restrict__ BtK, const u16* __restrict__ BtV,
    const float* __restrict__ bq, const float* __restrict__ bk, const float* __restrict__ bv,
    u16* __restrict__ Qo, u16* __restrict__ Kt, u16* __restrict__ Vt) {
  __shared__ u16 As[128 * 32];
  __shared__ u16 Bs[128 * 32];
  const int z = blockIdx.z;
  const u16* Bt = (z == 0) ? BtQ : (z == 1) ? BtK : BtV;
  const float* bias = (z == 0) ? bq : (z == 1) ? bk : bv;
  const int m0 = blockIdx.x * 128, n0 = blockIdx.y * 128;

  f32x4 acc[4][4];
#pragma unroll
  for (int i = 0; i < 4; ++i)
#pragma unroll
    for (int j = 0; j < 4; ++j) acc[i][j] = f32x4{0.f, 0.f, 0.f, 0.f};

  gemm_core32(A, Bt, As, Bs, m0, n0, acc);

  const int lane = threadIdx.x & 63, wave = threadIdx.x >> 6;
  const int wm = (wave >> 1) * 64, wn = (wave & 1) * 64;
  const int c = lane & 15, quad = lane >> 4;
#pragma unroll
  for (int ni = 0; ni < 4; ++ni) {
    int n = n0 + wn + ni * 16 + c;
    float bval = bias[n];
#pragma unroll
    for (int mi = 0; mi < 4; ++mi) {
      int mb = m0 + wm + mi * 16 + quad * 4;
      if (z == 2) {
        // Vt[((b*16+h)*64 + d)*512 + s]: s = m consecutive -> ushort4 store
        int bb = mb >> 9, s = mb & 511, hh = n >> 6, d = n & 63;
        ushort4 st;
        __hip_bfloat16 h0 = __float2bfloat16(acc[mi][ni][0] + bval); st.x = *(u16*)&h0;
        __hip_bfloat16 h1 = __float2bfloat16(acc[mi][ni][1] + bval); st.y = *(u16*)&h1;
        __hip_bfloat16 h2 = __float2bfloat16(acc[mi][ni][2] + bval); st.z = *(u16*)&h2;
        __hip_bfloat16 h3 = __float2bfloat16(acc[mi][ni][3] + bval); st.w = *(u16*)&h3;
        *(ushort4*)&Vt[(((size_t)(bb * 16 + hh) * 64 + d) << 9) + s] = st;
      } else {
#pragma unroll
        for (int r = 0; r < 4; ++r) {
          int m = mb + r;
          float val = acc[mi][ni][r] + bval;
          __hip_bfloat16 hb = __float2bfloat16(val);
          if (z == 0) {
            Qo[(size_t)m * 1024 + n] = *(u16*)&hb;
          } else {
            int bb = m >> 9, s = m & 511, hh = n >> 6, d = n & 63;
            Kt[(((size_t)(bb * 16 + hh) * 512 + s) << 6) + d] = *(u16*)&hb;
          }
        }
      }
    }
  }
}

// ---------------------------------------------------------------------------
// Output GEMM: C_f32 = A @ Bt^T + bias.  Grid (64 m, 8 n).
// ---------------------------------------------------------------------------
__global__ __launch_bounds__(256) void gemm_out(
    const u16* __restrict__ A, const u16* __restrict__ Bt,
    const float* __restrict__ bias, float* __restrict__ Cf) {
  __shared__ u16 As[128 * 32];
  __shared__ u16 Bs[128 * 32];
  const int m0 = blockIdx.x * 128, n0 = blockIdx.y * 128;

  f32x4 acc[4][4];
#pragma unroll
  for (int i = 0; i < 4; ++i)
#pragma unroll
    for (int j = 0; j < 4; ++j) acc[i][j] = f32x4{0.f, 0.f, 0.f, 0.f};

  gemm_core32(A, Bt, As, Bs, m0, n0, acc);

  const int lane = threadIdx.x & 63, wave = threadIdx.x >> 6;
  const int wm = (wave >> 1) * 64, wn = (wave & 1) * 64;
  const int c = lane & 15, quad = lane >> 4;
#pragma unroll
  for (int ni = 0; ni < 4; ++ni) {
    int n = n0 + wn + ni * 16 + c;
    float bval = bias[n];
#pragma unroll
    for (int mi = 0; mi < 4; ++mi) {
#pragma unroll
      for (int r = 0; r < 4; ++r) {
        int m = m0 + wm + mi * 16 + quad * 4 + r;
        Cf[(size_t)m * 1024 + n] = acc[mi][ni][r] + bval;
      }
    }
  }
}

// ---------------------------------------------------------------------------
// Attention v5: no-max softmax + TRANSPOSED score MFMA.
// S^T = K·Q^T via mfma(kfrag, qfrag): C-layout gives lane 4 consecutive KEYS
// (rows quad*4+r) for one q-row (col c) -> P staging is ds_write_b64 (4x fewer
// LDS writes than b16 scatter). PV unchanged (P read back in A-layout b128).
// Grid (4 qchunks, 16 heads, 16 batches); wave = 32 q rows; 64 keys/iter.
// ---------------------------------------------------------------------------
__global__ __launch_bounds__(256) void attn_v5(
    const u16* __restrict__ Q, const u16* __restrict__ Kt,
    const u16* __restrict__ Vt, const int* __restrict__ lengths,
    u16* __restrict__ O) {
  const int qc = blockIdx.x, h = blockIdx.y, b = blockIdx.z;
  const int t = threadIdx.x;
  const int lane = t & 63, wave = t >> 6;
  const int c = lane & 15, quad = lane >> 4;
  const int kb = quad * 8;
  const int len = lengths[b];
  const int q0 = qc * 128 + wave * 32;

  __shared__ __align__(16) u16 Pt[4][32 * 72];  // per-wave 32 q-rows x 64 keys, stride 72

  const size_t bBase = (size_t)b * (S_SZ * D_SZ);
  const size_t hBase = ((size_t)(b * H_SZ + h)) * (S_SZ * DH_SZ);

  short8 aq[2][2];
#pragma unroll
  for (int qt = 0; qt < 2; ++qt) {
    aq[qt][0] = *(const short8*)&Q[bBase + (size_t)(q0 + qt * 16 + c) * 1024 + h * 64 + kb];
    aq[qt][1] = *(const short8*)&Q[bBase + (size_t)(q0 + qt * 16 + c) * 1024 + h * 64 + 32 + kb];
  }

  float rs[2] = {0.f, 0.f};     // per-lane partial sum for q-row c (tile qt)
  f32x4 o[2][4];
#pragma unroll
  for (int qt = 0; qt < 2; ++qt)
#pragma unroll
    for (int i = 0; i < 4; ++i) o[qt][i] = f32x4{0.f, 0.f, 0.f, 0.f};

  const int kmax = (len + 63) & ~63;
  for (int k0 = 0; k0 < kmax; k0 += 64) {
    // --- S^T per 16-key sub-tile: rows = keys (quad*4+r), cols = q (c) ---
#pragma unroll
    for (int sub = 0; sub < 4; ++sub) {
      const int n0 = k0 + sub * 16;
      short8 bk0 = *(const short8*)&Kt[hBase + (size_t)(n0 + c) * 64 + kb];
      short8 bk1 = *(const short8*)&Kt[hBase + (size_t)(n0 + c) * 64 + 32 + kb];
      const int keyb = n0 + quad * 4;
#pragma unroll
      for (int qt = 0; qt < 2; ++qt) {
        f32x4 s = {0.f, 0.f, 0.f, 0.f};
        s = __builtin_amdgcn_mfma_f32_16x16x32_bf16(bk0, aq[qt][0], s, 0, 0, 0);
        s = __builtin_amdgcn_mfma_f32_16x16x32_bf16(bk1, aq[qt][1], s, 0, 0, 0);
        ushort4 st;
        float p0 = (keyb + 0) < len ? exp2f(s[0] * EXPSCALE) : 0.f;
        float p1 = (keyb + 1) < len ? exp2f(s[1] * EXPSCALE) : 0.f;
        float p2 = (keyb + 2) < len ? exp2f(s[2] * EXPSCALE) : 0.f;
        float p3 = (keyb + 3) < len ? exp2f(s[3] * EXPSCALE) : 0.f;
        __hip_bfloat16 h0 = __float2bfloat16(p0); st.x = *(u16*)&h0;
        __hip_bfloat16 h1 = __float2bfloat16(p1); st.y = *(u16*)&h1;
        __hip_bfloat16 h2 = __float2bfloat16(p2); st.z = *(u16*)&h2;
        __hip_bfloat16 h3 = __float2bfloat16(p3); st.w = *(u16*)&h3;
        rs[qt] += __bfloat162float(h0) + __bfloat162float(h1) +
                  __bfloat162float(h2) + __bfloat162float(h3);
        *(ushort4*)&Pt[wave][(qt * 16 + c) * 72 + sub * 16 + quad * 4] = st;
      }
    }
    // --- O += P @ V ---
#pragma unroll
    for (int ksub = 0; ksub < 2; ++ksub) {
      const short8 pa0 = *(const short8*)&Pt[wave][(c) * 72 + ksub * 32 + kb];
      const short8 pa1 = *(const short8*)&Pt[wave][(16 + c) * 72 + ksub * 32 + kb];
#pragma unroll
      for (int dt = 0; dt < 4; ++dt) {
        short8 vb = *(const short8*)&Vt[hBase + (size_t)(dt * 16 + c) * 512 + k0 + ksub * 32 + kb];
        o[0][dt] = __builtin_amdgcn_mfma_f32_16x16x32_bf16(pa0, vb, o[0][dt], 0, 0, 0);
        o[1][dt] = __builtin_amdgcn_mfma_f32_16x16x32_bf16(pa1, vb, o[1][dt], 0, 0, 0);
      }
    }
  }

  // --- finalize l: reduce across the 4 quads (lanes sharing c) ---
#pragma unroll
  for (int qt = 0; qt < 2; ++qt) {
    rs[qt] += __shfl_xor(rs[qt], 16, 64);
    rs[qt] += __shfl_xor(rs[qt], 32, 64);
  }

  // O rows are q = quad*4+r; l lives at lane c=q -> width-16 broadcast
#pragma unroll
  for (int qt = 0; qt < 2; ++qt) {
    float lq[4];
#pragma unroll
    for (int r = 0; r < 4; ++r) lq[r] = __shfl(rs[qt], quad * 4 + r, 16);
#pragma unroll
    for (int dt = 0; dt < 4; ++dt) {
#pragma unroll
      for (int r = 0; r < 4; ++r) {
        int s = q0 + qt * 16 + quad * 4 + r;
        float val = o[qt][dt][r] / lq[r];
        __hip_bfloat16 ob = __float2bfloat16(val);
        O[bBase + (size_t)s * 1024 + h * 64 + dt * 16 + c] = *(u16*)&ob;
      }
    }
  }
}

// ---------------------------------------------------------------------------
extern "C" void kernel_launch(void* const* d_in, const int* in_sizes, int n_in,
                              void* d_out, int out_size, void* d_ws, size_t ws_size,
                              hipStream_t stream) {
  const float* v  = (const float*)d_in[0];
  const int* lengths = (const int*)d_in[1];
  const float* Wq = (const float*)d_in[2];
  const float* bq = (const float*)d_in[3];
  const float* Wk = (const float*)d_in[4];
  const float* bk = (const float*)d_in[5];
  const float* Wv = (const float*)d_in[6];
  const float* bv = (const float*)d_in[7];
  const float* Wo = (const float*)d_in[8];
  const float* bo = (const float*)d_in[9];

  char* ws = (char*)d_ws;
  const size_t TSZ = (size_t)M_SZ * D_SZ * 2;   // 16 MiB bf16 activation tensor
  const size_t WSZ = (size_t)1 << 21;           // 2 MiB per transposed weight
  u16* vB  = (u16*)(ws);                        // aliased: AO reuses this after QKV
  u16* AO  = vB;
  u16* WqT = (u16*)(ws + TSZ + 0 * WSZ);
  u16* WkT = (u16*)(ws + TSZ + 1 * WSZ);
  u16* WvT = (u16*)(ws + TSZ + 2 * WSZ);
  u16* WoT = (u16*)(ws + TSZ + 3 * WSZ);
  u16* Qb  = (u16*)(ws + TSZ + 4 * WSZ + 0 * TSZ);
  u16* Kt  = (u16*)(ws + TSZ + 4 * WSZ + 1 * TSZ);
  u16* Vt  = (u16*)(ws + TSZ + 4 * WSZ + 2 * TSZ);

  prep<<<dim3(8192 + 4096), 256, 0, stream>>>(v, vB, Wq, Wk, Wv, Wo, WqT, WkT, WvT, WoT);

  gemm_qkv<<<dim3(64, 8, 3), 256, 0, stream>>>(vB, WqT, WkT, WvT, bq, bk, bv, Qb, Kt, Vt);

  attn_v5<<<dim3(4, 16, 16), 256, 0, stream>>>(Qb, Kt, Vt, lengths, AO);

  gemm_out<<<dim3(64, 8), 256, 0, stream>>>(AO, WoT, bo, (float*)d_out);
}

// Round 7
// 234.851 us; speedup vs baseline: 1.0734x; 1.0734x over previous
//
#include <hip/hip_runtime.h>
#include <hip/hip_bf16.h>

typedef unsigned short u16;
typedef __attribute__((ext_vector_type(8))) short short8;
typedef __attribute__((ext_vector_type(4))) float f32x4;

#define B_SZ 16
#define S_SZ 512
#define D_SZ 1024
#define H_SZ 16
#define DH_SZ 64
#define M_SZ (B_SZ * S_SZ)      // 8192
#define EXPSCALE 0.18033688f    // 0.125 * log2(e)

// direct global->LDS DMA, 16B per lane; LDS dest = wave-uniform base + lane*16
__device__ __forceinline__ void gload_lds16(const void* g, void* l) {
  __builtin_amdgcn_global_load_lds(
      (const __attribute__((address_space(1))) unsigned int*)g,
      (__attribute__((address_space(3))) unsigned int*)l,
      16, 0, 0);
}

// ---------------------------------------------------------------------------
// prep: fused f32->bf16 cast of v (blocks 0..8191) + weight transpose+downcast
// ---------------------------------------------------------------------------
__global__ __launch_bounds__(256) void prep(
    const float* __restrict__ v, u16* __restrict__ vB,
    const float* __restrict__ W0, const float* __restrict__ W1,
    const float* __restrict__ W2, const float* __restrict__ W3,
    u16* __restrict__ T0, u16* __restrict__ T1,
    u16* __restrict__ T2, u16* __restrict__ T3) {
  __shared__ float tile[32][33];
  const int bid = blockIdx.x;
  if (bid < 8192) {
    int i = bid * 256 + threadIdx.x;
    const float4 f = *(const float4*)&v[(size_t)i * 4];
    ushort4 o; __hip_bfloat16 h;
    h = __float2bfloat16(f.x); o.x = *(u16*)&h;
    h = __float2bfloat16(f.y); o.y = *(u16*)&h;
    h = __float2bfloat16(f.z); o.z = *(u16*)&h;
    h = __float2bfloat16(f.w); o.w = *(u16*)&h;
    *(ushort4*)&vB[(size_t)i * 4] = o;
    return;
  }
  const int tb = bid - 8192;
  const int z = tb >> 10, rem = tb & 1023;
  const int by = rem >> 5, bx = rem & 31;
  const float* W; u16* T;
  switch (z) {
    case 0: W = W0; T = T0; break;
    case 1: W = W1; T = T1; break;
    case 2: W = W2; T = T2; break;
    default: W = W3; T = T3; break;
  }
  int tx = threadIdx.x & 31, ty = threadIdx.x >> 5;  // 32 x 8
  int x = bx * 32 + tx;
#pragma unroll
  for (int i = 0; i < 32; i += 8)
    tile[ty + i][tx] = W[(size_t)(by * 32 + ty + i) * 1024 + x];
  __syncthreads();
  int x2 = by * 32 + tx;
#pragma unroll
  for (int i = 0; i < 32; i += 8) {
    __hip_bfloat16 h = __float2bfloat16(tile[tx][ty + i]);
    T[(size_t)(bx * 32 + ty + i) * 1024 + x2] = *(u16*)&h;
  }
}

// ---------------------------------------------------------------------------
// GEMM core: BK=32, XOR chunk swizzle (conflict-free, verified r6).
// ---------------------------------------------------------------------------
__device__ __forceinline__ void gemm_core32(
    const u16* __restrict__ A, const u16* __restrict__ Bt,
    u16* As, u16* Bs, int m0, int n0, f32x4 acc[4][4]) {
  const int t = threadIdx.x;
  const int lane = t & 63, wave = t >> 6;
  const int r4 = lane >> 2;
  const int gcol = ((lane & 3) ^ ((r4 >> 1) & 3)) * 8;
  const int wm = (wave >> 1) * 64, wn = (wave & 1) * 64;
  const int c = lane & 15, quad = lane >> 4;
  const int pc = (quad ^ ((c >> 1) & 3)) * 8;

  for (int k0 = 0; k0 < 1024; k0 += 32) {
    __syncthreads();
#pragma unroll
    for (int i = 0; i < 2; ++i) {
      int seg = wave * 2 + i;
      int row = seg * 16 + r4;
      gload_lds16(&A[(size_t)(m0 + row) * 1024 + k0 + gcol], &As[seg * 512]);
      gload_lds16(&Bt[(size_t)(n0 + row) * 1024 + k0 + gcol], &Bs[seg * 512]);
    }
    __syncthreads();

    short8 af[4], bf[4];
#pragma unroll
    for (int i = 0; i < 4; ++i) {
      af[i] = *(const short8*)&As[(wm + i * 16 + c) * 32 + pc];
      bf[i] = *(const short8*)&Bs[(wn + i * 16 + c) * 32 + pc];
    }
#pragma unroll
    for (int mi = 0; mi < 4; ++mi)
#pragma unroll
      for (int ni = 0; ni < 4; ++ni)
        acc[mi][ni] = __builtin_amdgcn_mfma_f32_16x16x32_bf16(
            af[mi], bf[ni], acc[mi][ni], 0, 0, 0);
  }
}

// ---------------------------------------------------------------------------
// Fused QKV GEMM. Grid (64 m, 8 n, 3 z) -> XCD = blockid%8 pins A-stripes.
// ---------------------------------------------------------------------------
__global__ __launch_bounds__(256) void gemm_qkv(
    const u16* __restrict__ A,
    const u16* __restrict__ BtQ, const u16* __restrict__ BtK, const u16* __restrict__ BtV,
    const float* __restrict__ bq, const float* __restrict__ bk, const float* __restrict__ bv,
    u16* __restrict__ Qo, u16* __restrict__ Kt, u16* __restrict__ Vt) {
  __shared__ u16 As[128 * 32];
  __shared__ u16 Bs[128 * 32];
  const int z = blockIdx.z;
  const u16* Bt = (z == 0) ? BtQ : (z == 1) ? BtK : BtV;
  const float* bias = (z == 0) ? bq : (z == 1) ? bk : bv;
  const int m0 = blockIdx.x * 128, n0 = blockIdx.y * 128;

  f32x4 acc[4][4];
#pragma unroll
  for (int i = 0; i < 4; ++i)
#pragma unroll
    for (int j = 0; j < 4; ++j) acc[i][j] = f32x4{0.f, 0.f, 0.f, 0.f};

  gemm_core32(A, Bt, As, Bs, m0, n0, acc);

  const int lane = threadIdx.x & 63, wave = threadIdx.x >> 6;
  const int wm = (wave >> 1) * 64, wn = (wave & 1) * 64;
  const int c = lane & 15, quad = lane >> 4;
#pragma unroll
  for (int ni = 0; ni < 4; ++ni) {
    int n = n0 + wn + ni * 16 + c;
    float bval = bias[n];
#pragma unroll
    for (int mi = 0; mi < 4; ++mi) {
      int mb = m0 + wm + mi * 16 + quad * 4;
      if (z == 2) {
        int bb = mb >> 9, s = mb & 511, hh = n >> 6, d = n & 63;
        ushort4 st;
        __hip_bfloat16 h0 = __float2bfloat16(acc[mi][ni][0] + bval); st.x = *(u16*)&h0;
        __hip_bfloat16 h1 = __float2bfloat16(acc[mi][ni][1] + bval); st.y = *(u16*)&h1;
        __hip_bfloat16 h2 = __float2bfloat16(acc[mi][ni][2] + bval); st.z = *(u16*)&h2;
        __hip_bfloat16 h3 = __float2bfloat16(acc[mi][ni][3] + bval); st.w = *(u16*)&h3;
        *(ushort4*)&Vt[(((size_t)(bb * 16 + hh) * 64 + d) << 9) + s] = st;
      } else {
#pragma unroll
        for (int r = 0; r < 4; ++r) {
          int m = mb + r;
          float val = acc[mi][ni][r] + bval;
          __hip_bfloat16 hb = __float2bfloat16(val);
          if (z == 0) {
            Qo[(size_t)m * 1024 + n] = *(u16*)&hb;
          } else {
            int bb = m >> 9, s = m & 511, hh = n >> 6, d = n & 63;
            Kt[(((size_t)(bb * 16 + hh) * 512 + s) << 6) + d] = *(u16*)&hb;
          }
        }
      }
    }
  }
}

// ---------------------------------------------------------------------------
// Output GEMM: C_f32 = A @ Bt^T + bias.  Grid (64 m, 8 n).
// ---------------------------------------------------------------------------
__global__ __launch_bounds__(256) void gemm_out(
    const u16* __restrict__ A, const u16* __restrict__ Bt,
    const float* __restrict__ bias, float* __restrict__ Cf) {
  __shared__ u16 As[128 * 32];
  __shared__ u16 Bs[128 * 32];
  const int m0 = blockIdx.x * 128, n0 = blockIdx.y * 128;

  f32x4 acc[4][4];
#pragma unroll
  for (int i = 0; i < 4; ++i)
#pragma unroll
    for (int j = 0; j < 4; ++j) acc[i][j] = f32x4{0.f, 0.f, 0.f, 0.f};

  gemm_core32(A, Bt, As, Bs, m0, n0, acc);

  const int lane = threadIdx.x & 63, wave = threadIdx.x >> 6;
  const int wm = (wave >> 1) * 64, wn = (wave & 1) * 64;
  const int c = lane & 15, quad = lane >> 4;
#pragma unroll
  for (int ni = 0; ni < 4; ++ni) {
    int n = n0 + wn + ni * 16 + c;
    float bval = bias[n];
#pragma unroll
    for (int mi = 0; mi < 4; ++mi) {
#pragma unroll
      for (int r = 0; r < 4; ++r) {
        int m = m0 + wm + mi * 16 + quad * 4 + r;
        Cf[(size_t)m * 1024 + n] = acc[mi][ni][r] + bval;
      }
    }
  }
}

// ---------------------------------------------------------------------------
// Attention v6: v5 (S^T MFMA, no-max softmax) + cooperative K/V LDS staging.
// Per 64-key iter the block DMAs K-tile (64 keys x 64 d) and V-tile
// (64 d x 64 s) into LDS once (XOR-swizzled 128B rows, phys = chunk^(row&7)),
// shared by all 4 waves -> 4x less L2 traffic, loads decoupled from compute.
// Grid (4 qchunks, 16 heads, 16 batches); wave = 32 q rows.
// ---------------------------------------------------------------------------
__global__ __launch_bounds__(256) void attn_v6(
    const u16* __restrict__ Q, const u16* __restrict__ Kt,
    const u16* __restrict__ Vt, const int* __restrict__ lengths,
    u16* __restrict__ O) {
  const int qc = blockIdx.x, h = blockIdx.y, b = blockIdx.z;
  const int t = threadIdx.x;
  const int lane = t & 63, wave = t >> 6;
  const int c = lane & 15, quad = lane >> 4;
  const int kb = quad * 8;
  const int len = lengths[b];
  const int q0 = qc * 128 + wave * 32;

  __shared__ __align__(16) u16 Ks[64 * 64];     // [key][d], swizzled
  __shared__ __align__(16) u16 Vs[64 * 64];     // [d][s],  swizzled
  __shared__ __align__(16) u16 Pt[4][32 * 72];  // per-wave P^T staging

  const size_t bBase = (size_t)b * (S_SZ * D_SZ);
  const size_t hBase = ((size_t)(b * H_SZ + h)) * (S_SZ * DH_SZ);

  short8 aq[2][2];
#pragma unroll
  for (int qt = 0; qt < 2; ++qt) {
    aq[qt][0] = *(const short8*)&Q[bBase + (size_t)(q0 + qt * 16 + c) * 1024 + h * 64 + kb];
    aq[qt][1] = *(const short8*)&Q[bBase + (size_t)(q0 + qt * 16 + c) * 1024 + h * 64 + 32 + kb];
  }

  // staging lane geometry: 8 rows x 8 chunks per 64-lane wave-group
  const int srow = lane >> 3;                 // row within 8-row group
  const int slc = (lane & 7) ^ srow;          // swizzled logical chunk

  float rs[2] = {0.f, 0.f};
  f32x4 o[2][4];
#pragma unroll
  for (int qt = 0; qt < 2; ++qt)
#pragma unroll
    for (int i = 0; i < 4; ++i) o[qt][i] = f32x4{0.f, 0.f, 0.f, 0.f};

  const int kmax = (len + 63) & ~63;
  for (int k0 = 0; k0 < kmax; k0 += 64) {
    __syncthreads();   // previous iter's LDS reads complete
#pragma unroll
    for (int g = 0; g < 2; ++g) {
      const int rb = (wave * 2 + g) * 8;      // row base (8 rows per DMA)
      gload_lds16(&Kt[hBase + (size_t)(k0 + rb + srow) * 64 + slc * 8],
                  &Ks[(wave * 2 + g) * 512]);
      gload_lds16(&Vt[hBase + (size_t)(rb + srow) * 512 + k0 + slc * 8],
                  &Vs[(wave * 2 + g) * 512]);
    }
    __syncthreads();   // DMA visible to all waves

    // --- S^T per 16-key sub-tile: rows = keys, cols = q ---
#pragma unroll
    for (int sub = 0; sub < 4; ++sub) {
      const int row = sub * 16 + c;
      short8 bk0 = *(const short8*)&Ks[row * 64 + ((quad ^ (c & 7))) * 8];
      short8 bk1 = *(const short8*)&Ks[row * 64 + (((4 + quad) ^ (c & 7))) * 8];
      const int keyb = k0 + sub * 16 + quad * 4;
#pragma unroll
      for (int qt = 0; qt < 2; ++qt) {
        f32x4 s = {0.f, 0.f, 0.f, 0.f};
        s = __builtin_amdgcn_mfma_f32_16x16x32_bf16(bk0, aq[qt][0], s, 0, 0, 0);
        s = __builtin_amdgcn_mfma_f32_16x16x32_bf16(bk1, aq[qt][1], s, 0, 0, 0);
        ushort4 st;
        float p0 = (keyb + 0) < len ? exp2f(s[0] * EXPSCALE) : 0.f;
        float p1 = (keyb + 1) < len ? exp2f(s[1] * EXPSCALE) : 0.f;
        float p2 = (keyb + 2) < len ? exp2f(s[2] * EXPSCALE) : 0.f;
        float p3 = (keyb + 3) < len ? exp2f(s[3] * EXPSCALE) : 0.f;
        __hip_bfloat16 h0 = __float2bfloat16(p0); st.x = *(u16*)&h0;
        __hip_bfloat16 h1 = __float2bfloat16(p1); st.y = *(u16*)&h1;
        __hip_bfloat16 h2 = __float2bfloat16(p2); st.z = *(u16*)&h2;
        __hip_bfloat16 h3 = __float2bfloat16(p3); st.w = *(u16*)&h3;
        rs[qt] += __bfloat162float(h0) + __bfloat162float(h1) +
                  __bfloat162float(h2) + __bfloat162float(h3);
        *(ushort4*)&Pt[wave][(qt * 16 + c) * 72 + sub * 16 + quad * 4] = st;
      }
    }
    // --- O += P @ V (V fragments from LDS) ---
#pragma unroll
    for (int ksub = 0; ksub < 2; ++ksub) {
      const short8 pa0 = *(const short8*)&Pt[wave][(c) * 72 + ksub * 32 + kb];
      const short8 pa1 = *(const short8*)&Pt[wave][(16 + c) * 72 + ksub * 32 + kb];
#pragma unroll
      for (int dt = 0; dt < 4; ++dt) {
        const int vrow = dt * 16 + c;
        short8 vb = *(const short8*)&Vs[vrow * 64 + (((ksub * 4 + quad) ^ (c & 7))) * 8];
        o[0][dt] = __builtin_amdgcn_mfma_f32_16x16x32_bf16(pa0, vb, o[0][dt], 0, 0, 0);
        o[1][dt] = __builtin_amdgcn_mfma_f32_16x16x32_bf16(pa1, vb, o[1][dt], 0, 0, 0);
      }
    }
  }

  // --- finalize l: reduce across the 4 quads (lanes sharing c) ---
#pragma unroll
  for (int qt = 0; qt < 2; ++qt) {
    rs[qt] += __shfl_xor(rs[qt], 16, 64);
    rs[qt] += __shfl_xor(rs[qt], 32, 64);
  }

#pragma unroll
  for (int qt = 0; qt < 2; ++qt) {
    float lq[4];
#pragma unroll
    for (int r = 0; r < 4; ++r) lq[r] = __shfl(rs[qt], quad * 4 + r, 16);
#pragma unroll
    for (int dt = 0; dt < 4; ++dt) {
#pragma unroll
      for (int r = 0; r < 4; ++r) {
        int s = q0 + qt * 16 + quad * 4 + r;
        float val = o[qt][dt][r] / lq[r];
        __hip_bfloat16 ob = __float2bfloat16(val);
        O[bBase + (size_t)s * 1024 + h * 64 + dt * 16 + c] = *(u16*)&ob;
      }
    }
  }
}

// ---------------------------------------------------------------------------
extern "C" void kernel_launch(void* const* d_in, const int* in_sizes, int n_in,
                              void* d_out, int out_size, void* d_ws, size_t ws_size,
                              hipStream_t stream) {
  const float* v  = (const float*)d_in[0];
  const int* lengths = (const int*)d_in[1];
  const float* Wq = (const float*)d_in[2];
  const float* bq = (const float*)d_in[3];
  const float* Wk = (const float*)d_in[4];
  const float* bk = (const float*)d_in[5];
  const float* Wv = (const float*)d_in[6];
  const float* bv = (const float*)d_in[7];
  const float* Wo = (const float*)d_in[8];
  const float* bo = (const float*)d_in[9];

  char* ws = (char*)d_ws;
  const size_t TSZ = (size_t)M_SZ * D_SZ * 2;   // 16 MiB bf16 activation tensor
  const size_t WSZ = (size_t)1 << 21;           // 2 MiB per transposed weight
  u16* vB  = (u16*)(ws);                        // aliased: AO reuses this after QKV
  u16* AO  = vB;
  u16* WqT = (u16*)(ws + TSZ + 0 * WSZ);
  u16* WkT = (u16*)(ws + TSZ + 1 * WSZ);
  u16* WvT = (u16*)(ws + TSZ + 2 * WSZ);
  u16* WoT = (u16*)(ws + TSZ + 3 * WSZ);
  u16* Qb  = (u16*)(ws + TSZ + 4 * WSZ + 0 * TSZ);
  u16* Kt  = (u16*)(ws + TSZ + 4 * WSZ + 1 * TSZ);
  u16* Vt  = (u16*)(ws + TSZ + 4 * WSZ + 2 * TSZ);

  prep<<<dim3(8192 + 4096), 256, 0, stream>>>(v, vB, Wq, Wk, Wv, Wo, WqT, WkT, WvT, WoT);

  gemm_qkv<<<dim3(64, 8, 3), 256, 0, stream>>>(vB, WqT, WkT, WvT, bq, bk, bv, Qb, Kt, Vt);

  attn_v6<<<dim3(4, 16, 16), 256, 0, stream>>>(Qb, Kt, Vt, lengths, AO);

  gemm_out<<<dim3(64, 8), 256, 0, stream>>>(AO, WoT, bo, (float*)d_out);
}